// Round 11
// baseline (353.560 us; speedup 1.0000x reference)
//
#include <hip/hip_runtime.h>
#include <hip/hip_bf16.h>
#include <stdint.h>

#define Bn 8
#define Tn 4096
#define En 1024
#define Hn 128
#define SCALE 0.08838834764831845f  // 1/sqrt(128)

typedef __attribute__((ext_vector_type(8))) short bf16x8;
typedef __attribute__((ext_vector_type(4))) float f32x4;

__device__ __forceinline__ float bf2f(unsigned short v) {
    return __uint_as_float(((unsigned int)v) << 16);
}
// RNE pack of two fp32 -> packed bf16x2 (v_cvt_pk_bf16_f32 on gfx950)
__device__ __forceinline__ unsigned int pkbf(float a, float b) {
    __hip_bfloat162 h = __float22bfloat162_rn(make_float2(a, b));
    union { __hip_bfloat162 h2; unsigned int u; } cv;
    cv.h2 = h;
    return cv.u;
}

// async global->LDS, 16B per lane, LDS dest = wave-uniform base + lane*16
__device__ __forceinline__ void gll16(const unsigned short* g, unsigned short* l) {
    __builtin_amdgcn_global_load_lds(
        (const __attribute__((address_space(1))) void*)g,
        (__attribute__((address_space(3))) void*)l, 16, 0, 0);
}

// ---------------------------------------------------------------------------
// cvtall: fused xcvt + wcvt (R10: one fewer launch).
// blocks [0,8192): x fp32 -> bf16 streaming, 16 elems/thread.
// blocks [8192,8216): W (1024x128 fp32) -> Wt (128x1024 bf16, transposed).
// ---------------------------------------------------------------------------
__global__ __launch_bounds__(256)
void cvtall(const float* __restrict__ x, unsigned short* __restrict__ xb,
            const float* __restrict__ Wq, const float* __restrict__ Wk,
            const float* __restrict__ Wv, unsigned short* __restrict__ wt3) {
    __shared__ unsigned short wl[128 * 132];  // [k][n] bf16, pad 132 (wcvt only)
    const int t = threadIdx.x;
    if (blockIdx.x < 8192) {
        const size_t i = ((size_t)blockIdx.x * 256 + t) * 16;
        const float4* src = (const float4*)(x + i);
        float4 a = src[0], b = src[1], c = src[2], d = src[3];
        uint4 o0, o1;
        o0.x = pkbf(a.x, a.y); o0.y = pkbf(a.z, a.w);
        o0.z = pkbf(b.x, b.y); o0.w = pkbf(b.z, b.w);
        o1.x = pkbf(c.x, c.y); o1.y = pkbf(c.z, c.w);
        o1.z = pkbf(d.x, d.y); o1.w = pkbf(d.z, d.w);
        *(uint4*)(xb + i) = o0;
        *(uint4*)(xb + i + 8) = o1;
        return;
    }
    const int bid2 = blockIdx.x - 8192;   // 0..23
    const int which = bid2 >> 3;
    const int k0 = (bid2 & 7) * 128;
    const float* W = (which == 0) ? Wq : (which == 1) ? Wk : Wv;
    unsigned short* wt = wt3 + (size_t)which * 131072;
#pragma unroll
    for (int i = 0; i < 16; ++i) {
        const int idx = t + i * 256;          // < 4096
        const int k = idx >> 5, c4 = idx & 31;
        float4 v = *(const float4*)&W[(size_t)(k0 + k) * Hn + c4 * 4];
        uint2 p;
        p.x = pkbf(v.x, v.y);
        p.y = pkbf(v.z, v.w);
        *(uint2*)&wl[k * 132 + c4 * 4] = p;
    }
    __syncthreads();
#pragma unroll
    for (int j = 0; j < 32; ++j) {
        const int idx = t + j * 256;          // < 8192
        const int n = idx >> 6, kp = idx & 63;
        unsigned int u = (unsigned int)wl[(2 * kp) * 132 + n] |
                         ((unsigned int)wl[(2 * kp + 1) * 132 + n] << 16);
        *(unsigned int*)&wt[(size_t)n * 1024 + k0 + 2 * kp] = u;
    }
}

// ---------------------------------------------------------------------------
// qkv2: all-bf16 QKV GEMM, 8 waves/block (verified round 7).
// ---------------------------------------------------------------------------
#define QSWZ(r, c) (((r) << 7) + ((c) ^ (((r) & 7) << 4)))  // 128B rows, byte addr

__global__ __launch_bounds__(512, 4)
void qkv2(const unsigned short* __restrict__ xb,
          const unsigned short* __restrict__ wt3,
          unsigned short* __restrict__ Qo,
          unsigned short* __restrict__ Ko,
          unsigned short* __restrict__ Vo) {
    const int mt = blockIdx.x;
    const int which = blockIdx.y;
    const unsigned short* wt = wt3 + (size_t)which * 131072;
    unsigned short* out = (which == 0) ? Qo : (which == 1) ? Ko : Vo;
    const float scale = (which == 0) ? SCALE : 1.0f;

    __shared__ alignas(16) unsigned short Xs[2][128 * 64];  // 32 KB
    __shared__ alignas(16) unsigned short Ws[2][128 * 64];  // 32 KB

    const int t = threadIdx.x;
    const int w = t >> 6;                 // 0..7
    const int lane = t & 63;
    const int quad = lane >> 4;
    const int l16 = lane & 15;
    const int r8 = lane >> 3;             // lane's row within 8-row gll slab
    const int cb = lane & 7;              // lane's 16B col-block

    const unsigned short* xtile = xb + (size_t)(mt * 128) * En;

    f32x4 acc[8];
#pragma unroll
    for (int nst = 0; nst < 8; ++nst) acc[nst] = (f32x4){0.f, 0.f, 0.f, 0.f};

    // stage tile kt into buffer buf: 2 gll16 for X + 2 for W per thread
    auto stage = [&](int buf, int kt) {
#pragma unroll
        for (int i = 0; i < 2; ++i) {
            const int row = w * 16 + i * 8 + r8;      // row&7 == r8
            gll16(xtile + (size_t)row * En + kt * 64 + ((cb ^ (row & 7)) * 8),
                  &Xs[buf][(w * 16 + i * 8) * 64]);
        }
#pragma unroll
        for (int i = 0; i < 2; ++i) {
            const int row = w * 16 + i * 8 + r8;
            gll16(wt + (size_t)row * 1024 + kt * 64 + ((cb ^ (row & 7)) * 8),
                  &Ws[buf][(w * 16 + i * 8) * 64]);
        }
    };

    stage(0, 0);
    __syncthreads();                      // drains prologue gll

    for (int kt = 0; kt < 16; ++kt) {
        const int buf = kt & 1;
        if (kt < 15) stage(buf ^ 1, kt + 1);   // buf^1 free since kt-1 barrier
        // ---- MFMA on buf (covers the in-flight gll latency) ----
        const char* xs = (const char*)Xs[buf];
        const char* ws = (const char*)Ws[buf];
#pragma unroll
        for (int ks = 0; ks < 2; ++ks) {
            bf16x8 af = *(const bf16x8*)(xs + QSWZ(w * 16 + l16, ks * 64 + quad * 16));
#pragma unroll
            for (int nst = 0; nst < 8; ++nst) {
                bf16x8 bfr = *(const bf16x8*)(ws + QSWZ(nst * 16 + l16, ks * 64 + quad * 16));
                acc[nst] = __builtin_amdgcn_mfma_f32_16x16x32_bf16(bfr, af, acc[nst], 0, 0, 0);
            }
        }
        if (kt < 15) __syncthreads();     // drains stage(kt+1); syncs buffers
    }

    // ---- epilogue: lane holds m = l16, n = nst*16 + quad*4 + r ----
    {
        const size_t rowbase = (size_t)(mt * 128 + w * 16 + l16) * Hn;
#pragma unroll
        for (int nst = 0; nst < 8; ++nst) {
            f32x4 v = acc[nst];
            uint2 pk;
            pk.x = pkbf(v[0] * scale, v[1] * scale);
            pk.y = pkbf(v[2] * scale, v[3] * scale);
            *(uint2*)(out + rowbase + nst * 16 + quad * 4) = pk;
        }
    }
}

// ---------------------------------------------------------------------------
// Legacy fused-convert QKV (fallback if workspace too small for xb/wt).
// ---------------------------------------------------------------------------
__global__ __launch_bounds__(256)
void qkv_mfma(const float* __restrict__ x,
              const float* __restrict__ Wq,
              const float* __restrict__ Wk,
              const float* __restrict__ Wv,
              unsigned short* __restrict__ Qo,
              unsigned short* __restrict__ Ko,
              unsigned short* __restrict__ Vo) {
    const int mt = blockIdx.x;
    const int which = blockIdx.y;
    const float* W = (which == 0) ? Wq : (which == 1) ? Wk : Wv;
    unsigned short* out = (which == 0) ? Qo : (which == 1) ? Ko : Vo;
    const float scale = (which == 0) ? SCALE : 1.0f;

    __shared__ alignas(16) unsigned short Xs[128 * 72];
    __shared__ alignas(16) unsigned short Wt[128 * 72];

    const int t = threadIdx.x;
    const int w = t >> 6;
    const int lane = t & 63;
    const int quad = lane >> 4;
    const int l16 = lane & 15;

    const int xrow = t >> 1;
    const int xkc = (t & 1) * 32;
    const int ws0 = (t & 31) * 2;
    const int wd0 = (t >> 5) * 16;

    const float* xsrc0 = x + (size_t)(mt * 128 + xrow) * En + xkc;

    f32x4 acc[2][8];
#pragma unroll
    for (int mi = 0; mi < 2; ++mi)
#pragma unroll
        for (int nst = 0; nst < 8; ++nst) acc[mi][nst] = (f32x4){0.f, 0.f, 0.f, 0.f};

    float4 xpre[8], wpre[8];
    {
        const float* src = xsrc0;
#pragma unroll
        for (int i = 0; i < 8; ++i) xpre[i] = *(const float4*)(src + i * 4);
        const float* w0 = W + (size_t)ws0 * Hn + wd0;
        const float* w1 = w0 + Hn;
#pragma unroll
        for (int i = 0; i < 4; ++i) wpre[i] = *(const float4*)(w0 + i * 4);
#pragma unroll
        for (int i = 0; i < 4; ++i) wpre[4 + i] = *(const float4*)(w1 + i * 4);
    }

    for (int kt = 0; kt < 16; ++kt) {
        __syncthreads();
        {
            unsigned int u[16];
#pragma unroll
            for (int i = 0; i < 8; ++i) {
                u[2 * i]     = pkbf(xpre[i].x, xpre[i].y);
                u[2 * i + 1] = pkbf(xpre[i].z, xpre[i].w);
            }
#pragma unroll
            for (int i = 0; i < 4; ++i)
                *(uint4*)&Xs[xrow * 72 + xkc + i * 8] = ((const uint4*)u)[i];

            const float* ax = (const float*)&wpre[0];
            const float* bx = (const float*)&wpre[4];
#pragma unroll
            for (int dd = 0; dd < 16; ++dd)
                *(unsigned int*)&Wt[(wd0 + dd) * 72 + ws0] = pkbf(ax[dd], bx[dd]);
        }
        if (kt < 15) {
            const float* src = xsrc0 + (kt + 1) * 64;
#pragma unroll
            for (int i = 0; i < 8; ++i) xpre[i] = *(const float4*)(src + i * 4);
            const float* w0 = W + (size_t)((kt + 1) * 64 + ws0) * Hn + wd0;
            const float* w1 = w0 + Hn;
#pragma unroll
            for (int i = 0; i < 4; ++i) wpre[i] = *(const float4*)(w0 + i * 4);
#pragma unroll
            for (int i = 0; i < 4; ++i) wpre[4 + i] = *(const float4*)(w1 + i * 4);
        }
        __syncthreads();

#pragma unroll
        for (int ks = 0; ks < 2; ++ks) {
            bf16x8 af[2];
#pragma unroll
            for (int mi = 0; mi < 2; ++mi)
                af[mi] = *(const bf16x8*)&Xs[(w * 32 + mi * 16 + l16) * 72 + ks * 32 + quad * 8];
#pragma unroll
            for (int nst = 0; nst < 8; ++nst) {
                bf16x8 bfr = *(const bf16x8*)&Wt[(nst * 16 + l16) * 72 + ks * 32 + quad * 8];
                acc[0][nst] = __builtin_amdgcn_mfma_f32_16x16x32_bf16(bfr, af[0], acc[0][nst], 0, 0, 0);
                acc[1][nst] = __builtin_amdgcn_mfma_f32_16x16x32_bf16(bfr, af[1], acc[1][nst], 0, 0, 0);
            }
        }
    }

#pragma unroll
    for (int mi = 0; mi < 2; ++mi) {
        const size_t rowbase = (size_t)(mt * 128 + w * 32 + mi * 16 + l16) * Hn;
#pragma unroll
        for (int nst = 0; nst < 8; ++nst) {
            f32x4 v = acc[mi][nst];
            uint2 pk;
            pk.x = pkbf(v[0] * scale, v[1] * scale);
            pk.y = pkbf(v[2] * scale, v[3] * scale);
            *(uint2*)(out + rowbase + nst * 16 + quad * 4) = pk;
        }
    }
}

// ---------------------------------------------------------------------------
// MFMA flash attention v6.1 = verified R8 inner loop, split-K generalized to
// any gridDim.z (z=4 default: max 8-9 rounds/block, 2048 blocks, finer
// dynamic packing, tail halved vs z=2). Partition formula verified equal to
// R8's h0 at z=2. Register budget untouched (R9 lesson: the (512,4) 128-reg
// budget is exactly full; additions spill, occupancy trades lose).
// ---------------------------------------------------------------------------
#define KSWZ(r, c) (((r) << 8) + ((c) ^ (((r) & 7) << 4)))  // 256B rows (K/Q)
#define VSWZ(r, c) (((r) << 7) + ((c) ^ (((r) & 7) << 4)))  // 128B rows (V/P)

__global__ __launch_bounds__(512, 4)
void flash_mfma(const unsigned short* __restrict__ Qb,
                const unsigned short* __restrict__ Kb,
                const unsigned short* __restrict__ Vb,
                float* __restrict__ out,
                float* __restrict__ Up,      // [NZ][Bn*Tn][Hn] partials (split)
                float2* __restrict__ MLp) {  // [NZ][Bn*Tn] (m, l) (split)
    const int b = blockIdx.x;                     // batch
    const int bx = blockIdx.y;
    const int qt = (bx < 32) ? (63 - bx) : (bx - 32);
    const int z = blockIdx.z;
    const int NZ = gridDim.z;
    const bool split = (NZ > 1);
    // partition [0, qt+1) into NZ block-uniform ranges (== R8's h0 at NZ=2)
    const int q = qt + 1;
    const int base = q / NZ;
    const int rem = q % NZ;
    const int lo = z * base + (z < rem ? z : rem);
    const int hi = lo + base + (z < rem ? 1 : 0);
    const int R = hi - lo;                        // block-uniform (may be 0)
    const int t = threadIdx.x;
    const int w = t >> 6;                         // 0..7
    const int g = w >> 2;                         // kv-parity group (0=even,1=odd)
    const int rg = w & 3;                         // q row-group / group-local wave
    const int lane = t & 63;
    const int quad = lane >> 4;
    const int l16 = lane & 15;
    const int t256 = t & 255;                     // group-local thread id

    extern __shared__ unsigned short pool[];      // 40960 shorts = 80 KB
    char* const poolb = (char*)pool;
    char* const Kg = poolb + g * 16384;           // [64][128] bf16, swizzled
    char* const Vg = poolb + 32768 + g * 16384;   // [128][64] bf16 (V^T), swizzled
    char* const Pw = poolb + 65536 + w * 2048;    // per-wave [16][64] bf16, swizzled
    float* const Os = (float*)poolb;              // [64][132] f32 (epilogue overlay)
    float* const Ex = (float*)(poolb + 40960);    // [4][16][128] f32 (combine overlay)
    float* const Em = (float*)(poolb + 73728);    // [4][16] partial m
    float* const El = Em + 64;                    // [4][16] partial l

    const size_t gbase = (size_t)b * ((size_t)Tn * Hn);
    const unsigned short* kbase = Kb + gbase;
    const unsigned short* vbase = Vb + gbase;

    // staging coords
    const int l_hi = lane >> 4;                   // 0..3
    const int cpr = (lane & 15) * 16;             // byte col, pre-swizzle (Q/K gll)
    const int vs0 = (t256 & 31) * 2;              // V transpose-pack coords
    const int vd0 = (t256 >> 5) * 16;

    // ---- prefetch this group's V tile (kt = lo + g) ----
    uint4 vra, vrb, vrc, vrd;
    if (lo + g < hi) {
        const unsigned short* vsrc = vbase + (size_t)((lo + g) * 64) * Hn;
        vra = *(const uint4*)&vsrc[vs0 * 128 + vd0];
        vrb = *(const uint4*)&vsrc[vs0 * 128 + vd0 + 8];
        vrc = *(const uint4*)&vsrc[(vs0 + 1) * 128 + vd0];
        vrd = *(const uint4*)&vsrc[(vs0 + 1) * 128 + vd0 + 8];
    }

    // ---- stage Q tile (into group-0 K region) via global_load_lds ----
    {
        const unsigned short* qsrc = Qb + gbase + (size_t)(qt * 64) * Hn;
#pragma unroll
        for (int i = 0; i < 2; ++i) {
            const int row = w * 8 + i * 4 + l_hi;
            const int scol = cpr ^ ((row & 7) << 4);
            gll16(qsrc + row * 128 + (scol >> 1),
                  (unsigned short*)(poolb + w * 2048 + i * 1024));
        }
    }
    __syncthreads();

    // hoist Q B-frags: lane holds Q[q=l16 of row-group rg][d=ks*32+quad*8+j]
    bf16x8 qf[4];
#pragma unroll
    for (int ks = 0; ks < 4; ++ks)
        qf[ks] = *(const bf16x8*)(poolb + KSWZ(rg * 16 + l16, ks * 64 + quad * 16));

    f32x4 acc_o[8];
#pragma unroll
    for (int i = 0; i < 8; ++i) acc_o[i] = (f32x4){0.f, 0.f, 0.f, 0.f};
    float m_run = -1e30f, l_run = 0.f;

    const int n = (R + 1) >> 1;                   // group-0 trip count (>= group-1)
    for (int it = 0; it < n; ++it) {
        const int kt = lo + 2 * it + g;
        const bool active = (kt < hi);
        __syncthreads();                          // prev compute done; Kg/Vg free
        if (active) {
            // ---- K: direct global->LDS, pre-swizzled source, 4 instrs/wave
            const unsigned short* ktile = kbase + (size_t)(kt * 64) * Hn;
#pragma unroll
            for (int i = 0; i < 4; ++i) {
                const int row = rg * 16 + i * 4 + l_hi;
                const int scol = cpr ^ ((row & 7) << 4);
                gll16(ktile + row * 128 + (scol >> 1),
                      (unsigned short*)(Kg + rg * 4096 + i * 1024));
            }
            // ---- V: staged regs -> LDS transpose-pack ----
            const unsigned short* pa = (const unsigned short*)&vra;
            const unsigned short* pb = (const unsigned short*)&vrb;
            const unsigned short* pc = (const unsigned short*)&vrc;
            const unsigned short* pd = (const unsigned short*)&vrd;
#pragma unroll
            for (int dd = 0; dd < 8; ++dd)
                *(unsigned int*)(Vg + VSWZ(vd0 + dd, vs0 * 2)) =
                    (unsigned int)pa[dd] | ((unsigned int)pc[dd] << 16);
#pragma unroll
            for (int dd = 0; dd < 8; ++dd)
                *(unsigned int*)(Vg + VSWZ(vd0 + 8 + dd, vs0 * 2)) =
                    (unsigned int)pb[dd] | ((unsigned int)pd[dd] << 16);
        }
        __syncthreads();                          // drains K gll + V ds_writes
        // ---- issue next V loads AFTER barrier: drain lands next round ----
        if (kt + 2 < hi) {
            const unsigned short* vsrc = vbase + (size_t)((kt + 2) * 64) * Hn;
            vra = *(const uint4*)&vsrc[vs0 * 128 + vd0];
            vrb = *(const uint4*)&vsrc[vs0 * 128 + vd0 + 8];
            vrc = *(const uint4*)&vsrc[(vs0 + 1) * 128 + vd0];
            vrd = *(const uint4*)&vsrc[(vs0 + 1) * 128 + vd0 + 8];
        }
        if (!active) continue;                    // barriers done; skip compute

        const bool diag = (kt == qt);
        // S^T = K.Q^T ; lane holds S[q=l16][s=st*16+quad*4+r]
        f32x4 sa[4];
#pragma unroll
        for (int st = 0; st < 4; ++st) {
            if (diag && st > rg) {
                sa[st] = (f32x4){-1e30f, -1e30f, -1e30f, -1e30f};  // fully masked
            } else {
                f32x4 c = (f32x4){0.f, 0.f, 0.f, 0.f};
#pragma unroll
                for (int ks = 0; ks < 4; ++ks) {
                    bf16x8 kf = *(const bf16x8*)(Kg + KSWZ(st * 16 + l16, ks * 64 + quad * 16));
                    c = __builtin_amdgcn_mfma_f32_16x16x32_bf16(kf, qf[ks], c, 0, 0, 0);
                }
                if (diag && st == rg) {
#pragma unroll
                    for (int r = 0; r < 4; ++r)
                        if (quad * 4 + r > l16) c[r] = -1e30f;
                }
                sa[st] = c;
            }
        }

        // row max (max3-friendly tree), replicated across the 4 quads
        float t0 = fmaxf(fmaxf(sa[0][0], sa[0][1]), fmaxf(sa[0][2], sa[0][3]));
        float t1 = fmaxf(fmaxf(sa[1][0], sa[1][1]), fmaxf(sa[1][2], sa[1][3]));
        float t2 = fmaxf(fmaxf(sa[2][0], sa[2][1]), fmaxf(sa[2][2], sa[2][3]));
        float t3 = fmaxf(fmaxf(sa[3][0], sa[3][1]), fmaxf(sa[3][2], sa[3][3]));
        float mloc = fmaxf(fmaxf(t0, t1), fmaxf(t2, t3));
        mloc = fmaxf(mloc, __shfl_xor(mloc, 16));
        mloc = fmaxf(mloc, __shfl_xor(mloc, 32));

        // T13 defer-max: skip rescale when no row grew past m_run+8.
        if (!__all(mloc <= m_run + 8.0f)) {
            const float m_new = fmaxf(m_run, mloc);
            const float alpha = __expf(m_run - m_new);
            l_run *= alpha;
#pragma unroll
            for (int i = 0; i < 8; ++i) acc_o[i] *= alpha;
            m_run = m_new;
        }
        float lsum = 0.f;
#pragma unroll
        for (int st = 0; st < 4; ++st)
#pragma unroll
            for (int r = 0; r < 4; ++r) {
                const float e = __expf(sa[st][r] - m_run);
                sa[st][r] = e;                    // exp in place
                lsum += e;
            }
        lsum += __shfl_xor(lsum, 16);
        lsum += __shfl_xor(lsum, 32);
        l_run += lsum;

        // P (C-layout) -> per-wave LDS -> P^T B-frags (same-wave, no barrier)
#pragma unroll
        for (int st = 0; st < 4; ++st) {
            uint2 pk;
            pk.x = pkbf(sa[st][0], sa[st][1]);
            pk.y = pkbf(sa[st][2], sa[st][3]);
            *(uint2*)(Pw + VSWZ(l16, st * 32 + quad * 8)) = pk;
        }
        bf16x8 pf0 = *(const bf16x8*)(Pw + VSWZ(l16, quad * 16));
        bf16x8 pf1 = *(const bf16x8*)(Pw + VSWZ(l16, 64 + quad * 16));

        // O^T += V^T . P^T
#pragma unroll
        for (int dt = 0; dt < 8; ++dt) {
            bf16x8 vf0 = *(const bf16x8*)(Vg + VSWZ(dt * 16 + l16, quad * 16));
            acc_o[dt] = __builtin_amdgcn_mfma_f32_16x16x32_bf16(vf0, pf0, acc_o[dt], 0, 0, 0);
            bf16x8 vf1 = *(const bf16x8*)(Vg + VSWZ(dt * 16 + l16, 64 + quad * 16));
            acc_o[dt] = __builtin_amdgcn_mfma_f32_16x16x32_bf16(vf1, pf1, acc_o[dt], 0, 0, 0);
        }
    }

    // ---- in-block flash combine: group 1 publishes (m,l,O); group 0 merges ----
    __syncthreads();
    if (g == 1) {
        float* dst = Ex + (rg * 16 + l16) * 128;
#pragma unroll
        for (int dt = 0; dt < 8; ++dt)
            *(f32x4*)&dst[dt * 16 + quad * 4] = acc_o[dt];
        if (quad == 0) {
            Em[rg * 16 + l16] = m_run;
            El[rg * 16 + l16] = l_run;
        }
    }
    __syncthreads();
    if (g == 0) {
        const float* src = Ex + (rg * 16 + l16) * 128;
        const float m2 = Em[rg * 16 + l16];
        const float l2 = El[rg * 16 + l16];
        const float ms = fmaxf(m_run, m2);
        const float a1 = __expf(m_run - ms);
        const float a2 = __expf(m2 - ms);
        const float den = l_run * a1 + l2 * a2;
        const float scl = split ? 1.f : (1.f / den);
#pragma unroll
        for (int dt = 0; dt < 8; ++dt) {
            f32x4 o2 = *(const f32x4*)&src[dt * 16 + quad * 4];
            f32x4 v = (acc_o[dt] * a1 + o2 * a2) * scl;
            *(f32x4*)&Os[(rg * 16 + l16) * 132 + dt * 16 + quad * 4] = v;
        }
        if (split && quad == 0)
            MLp[(size_t)z * (Bn * Tn) + (size_t)b * Tn + qt * 64 + rg * 16 + l16] =
                make_float2(ms, den);
    }
    __syncthreads();
    // coalesced fp32 stores, all 512 threads
    float* dst = split
        ? (Up + ((size_t)z * Bn * Tn + (size_t)b * Tn + (size_t)qt * 64) * Hn)
        : (out + gbase + (size_t)(qt * 64) * Hn);
#pragma unroll
    for (int i = 0; i < 4; ++i) {
        const int idx = (t + i * 512) * 4;
        const int row = idx >> 7, col = idx & 127;
        *(float4*)&dst[row * 128 + col] = *(const float4*)&Os[row * 132 + col];
    }
}

// ---------------------------------------------------------------------------
// fcomb: merge nz split-K partials. 1,048,576 f32x4 quads, 4096 blocks.
// out = (Σ a_z U_z) / (Σ a_z l_z), a_z = exp(m_z - max_z m). Empty partials
// (m=-1e30, l=0) contribute a_z*l_z = 0 and a_z*U_z = 0 -- safe for R=0.
// ---------------------------------------------------------------------------
__global__ __launch_bounds__(256)
void fcomb(const float* __restrict__ U, const float2* __restrict__ ml,
           float* __restrict__ out, int nz) {
    const size_t i = (size_t)blockIdx.x * 256 + threadIdx.x;   // quad index
    const size_t grow = i >> 5;                                // global q-row
    const int c4 = (int)(i & 31) * 4;
    float m[4], l[4];
    float ms = -1e30f;
#pragma unroll 4
    for (int zz = 0; zz < nz; ++zz) {
        const float2 p = ml[(size_t)zz * (Bn * Tn) + grow];
        m[zz] = p.x; l[zz] = p.y;
        ms = fmaxf(ms, p.x);
    }
    f32x4 v = (f32x4){0.f, 0.f, 0.f, 0.f};
    float den = 0.f;
#pragma unroll 4
    for (int zz = 0; zz < nz; ++zz) {
        const float a = __expf(m[zz] - ms);
        den += a * l[zz];
        const f32x4 u = *(const f32x4*)&U[(size_t)zz * Bn * Tn * Hn + grow * Hn + c4];
        v += u * a;
    }
    *(f32x4*)&out[grow * Hn + c4] = v * (1.f / den);
}

// ---------------------------------------------------------------------------
extern "C" void kernel_launch(void* const* d_in, const int* in_sizes, int n_in,
                              void* d_out, int out_size, void* d_ws, size_t ws_size,
                              hipStream_t stream) {
    const float* x  = (const float*)d_in[0];
    const float* Wq = (const float*)d_in[1];
    const float* Wk = (const float*)d_in[2];
    const float* Wv = (const float*)d_in[3];
    float* o = (float*)d_out;            // output fp32 (verified round 4)

    const size_t qkvb = (size_t)Bn * Tn * Hn;          // 4,194,304 elems
    unsigned short* Qb = (unsigned short*)d_ws;        // (B*T, H) bf16
    unsigned short* Kb = Qb + qkvb;
    unsigned short* Vb = Kb + qkvb;
    unsigned short* xbf = Vb + qkvb;                   // (B*T, E) bf16, 67 MB
    unsigned short* wt3 = xbf + (size_t)Bn * Tn * En;  // 3 x (H, E) bf16

    // z=2: U (33.5 MB) + ML inside the xbf region (R8-verified layout).
    // z=4: U (67.1 MB) fills xbf exactly; ML (1.05 MB) goes after wt3.
    float* Up = (float*)xbf;
    float2* ml2 = (float2*)((char*)xbf + (size_t)2 * Bn * Tn * Hn * sizeof(float));
    float2* ml4 = (float2*)(wt3 + (size_t)3 * Hn * En);

    const size_t need2 = (3 * qkvb + (size_t)Bn * Tn * En + 3 * (size_t)Hn * En)
                         * sizeof(unsigned short);
    const size_t need4 = need2 + (size_t)4 * Bn * Tn * sizeof(float2);

    static bool attr_done = false;
    if (!attr_done) {
        hipFuncSetAttribute((const void*)flash_mfma,
                            hipFuncAttributeMaxDynamicSharedMemorySize, 81920);
        attr_done = true;
    }

    if (ws_size >= need2) {
        cvtall<<<8216, 256, 0, stream>>>(x, xbf, Wq, Wk, Wv, wt3);
        qkv2<<<dim3(256, 3), 512, 0, stream>>>(xbf, wt3, Qb, Kb, Vb);
        if (ws_size >= need4) {
            flash_mfma<<<dim3(8, 64, 4), 512, 81920, stream>>>(Qb, Kb, Vb, o, Up, ml4);
            fcomb<<<4096, 256, 0, stream>>>(Up, ml4, o, 4);
        } else {
            flash_mfma<<<dim3(8, 64, 2), 512, 81920, stream>>>(Qb, Kb, Vb, o, Up, ml2);
            fcomb<<<4096, 256, 0, stream>>>(Up, ml2, o, 2);
        }
    } else {
        qkv_mfma<<<dim3(256, 3), 256, 0, stream>>>(x, Wq, Wk, Wv, Qb, Kb, Vb);
        flash_mfma<<<dim3(8, 64, 1), 512, 81920, stream>>>(Qb, Kb, Vb, o,
                                                           nullptr, nullptr);
    }
}

// Round 12
// 339.060 us; speedup vs baseline: 1.0428x; 1.0428x over previous
//
#include <hip/hip_runtime.h>
#include <hip/hip_bf16.h>
#include <stdint.h>

#define Bn 8
#define Tn 4096
#define En 1024
#define Hn 128
#define SCALE 0.08838834764831845f  // 1/sqrt(128)

typedef __attribute__((ext_vector_type(8))) short bf16x8;
typedef __attribute__((ext_vector_type(4))) float f32x4;

__device__ __forceinline__ float bf2f(unsigned short v) {
    return __uint_as_float(((unsigned int)v) << 16);
}
// RNE pack of two fp32 -> packed bf16x2 (v_cvt_pk_bf16_f32 on gfx950)
__device__ __forceinline__ unsigned int pkbf(float a, float b) {
    __hip_bfloat162 h = __float22bfloat162_rn(make_float2(a, b));
    union { __hip_bfloat162 h2; unsigned int u; } cv;
    cv.h2 = h;
    return cv.u;
}

// async global->LDS, 16B per lane, LDS dest = wave-uniform base + lane*16
__device__ __forceinline__ void gll16(const unsigned short* g, unsigned short* l) {
    __builtin_amdgcn_global_load_lds(
        (const __attribute__((address_space(1))) void*)g,
        (__attribute__((address_space(3))) void*)l, 16, 0, 0);
}

// ---------------------------------------------------------------------------
// cvtall: fused xcvt + wcvt (neutral-positive, kept from R11).
// blocks [0,8192): x fp32 -> bf16 streaming, 16 elems/thread.
// blocks [8192,8216): W (1024x128 fp32) -> Wt (128x1024 bf16, transposed).
// ---------------------------------------------------------------------------
__global__ __launch_bounds__(256)
void cvtall(const float* __restrict__ x, unsigned short* __restrict__ xb,
            const float* __restrict__ Wq, const float* __restrict__ Wk,
            const float* __restrict__ Wv, unsigned short* __restrict__ wt3) {
    __shared__ unsigned short wl[128 * 132];  // [k][n] bf16, pad 132 (wcvt only)
    const int t = threadIdx.x;
    if (blockIdx.x < 8192) {
        const size_t i = ((size_t)blockIdx.x * 256 + t) * 16;
        const float4* src = (const float4*)(x + i);
        float4 a = src[0], b = src[1], c = src[2], d = src[3];
        uint4 o0, o1;
        o0.x = pkbf(a.x, a.y); o0.y = pkbf(a.z, a.w);
        o0.z = pkbf(b.x, b.y); o0.w = pkbf(b.z, b.w);
        o1.x = pkbf(c.x, c.y); o1.y = pkbf(c.z, c.w);
        o1.z = pkbf(d.x, d.y); o1.w = pkbf(d.z, d.w);
        *(uint4*)(xb + i) = o0;
        *(uint4*)(xb + i + 8) = o1;
        return;
    }
    const int bid2 = blockIdx.x - 8192;   // 0..23
    const int which = bid2 >> 3;
    const int k0 = (bid2 & 7) * 128;
    const float* W = (which == 0) ? Wq : (which == 1) ? Wk : Wv;
    unsigned short* wt = wt3 + (size_t)which * 131072;
#pragma unroll
    for (int i = 0; i < 16; ++i) {
        const int idx = t + i * 256;          // < 4096
        const int k = idx >> 5, c4 = idx & 31;
        float4 v = *(const float4*)&W[(size_t)(k0 + k) * Hn + c4 * 4];
        uint2 p;
        p.x = pkbf(v.x, v.y);
        p.y = pkbf(v.z, v.w);
        *(uint2*)&wl[k * 132 + c4 * 4] = p;
    }
    __syncthreads();
#pragma unroll
    for (int j = 0; j < 32; ++j) {
        const int idx = t + j * 256;          // < 8192
        const int n = idx >> 6, kp = idx & 63;
        unsigned int u = (unsigned int)wl[(2 * kp) * 132 + n] |
                         ((unsigned int)wl[(2 * kp + 1) * 132 + n] << 16);
        *(unsigned int*)&wt[(size_t)n * 1024 + k0 + 2 * kp] = u;
    }
}

// ---------------------------------------------------------------------------
// qkv2: all-bf16 QKV GEMM, 8 waves/block (verified round 7).
// ---------------------------------------------------------------------------
#define QSWZ(r, c) (((r) << 7) + ((c) ^ (((r) & 7) << 4)))  // 128B rows, byte addr

__global__ __launch_bounds__(512, 4)
void qkv2(const unsigned short* __restrict__ xb,
          const unsigned short* __restrict__ wt3,
          unsigned short* __restrict__ Qo,
          unsigned short* __restrict__ Ko,
          unsigned short* __restrict__ Vo) {
    const int mt = blockIdx.x;
    const int which = blockIdx.y;
    const unsigned short* wt = wt3 + (size_t)which * 131072;
    unsigned short* out = (which == 0) ? Qo : (which == 1) ? Ko : Vo;
    const float scale = (which == 0) ? SCALE : 1.0f;

    __shared__ alignas(16) unsigned short Xs[2][128 * 64];  // 32 KB
    __shared__ alignas(16) unsigned short Ws[2][128 * 64];  // 32 KB

    const int t = threadIdx.x;
    const int w = t >> 6;                 // 0..7
    const int lane = t & 63;
    const int quad = lane >> 4;
    const int l16 = lane & 15;
    const int r8 = lane >> 3;             // lane's row within 8-row gll slab
    const int cb = lane & 7;              // lane's 16B col-block

    const unsigned short* xtile = xb + (size_t)(mt * 128) * En;

    f32x4 acc[8];
#pragma unroll
    for (int nst = 0; nst < 8; ++nst) acc[nst] = (f32x4){0.f, 0.f, 0.f, 0.f};

    // stage tile kt into buffer buf: 2 gll16 for X + 2 for W per thread
    auto stage = [&](int buf, int kt) {
#pragma unroll
        for (int i = 0; i < 2; ++i) {
            const int row = w * 16 + i * 8 + r8;      // row&7 == r8
            gll16(xtile + (size_t)row * En + kt * 64 + ((cb ^ (row & 7)) * 8),
                  &Xs[buf][(w * 16 + i * 8) * 64]);
        }
#pragma unroll
        for (int i = 0; i < 2; ++i) {
            const int row = w * 16 + i * 8 + r8;
            gll16(wt + (size_t)row * 1024 + kt * 64 + ((cb ^ (row & 7)) * 8),
                  &Ws[buf][(w * 16 + i * 8) * 64]);
        }
    };

    stage(0, 0);
    __syncthreads();                      // drains prologue gll

    for (int kt = 0; kt < 16; ++kt) {
        const int buf = kt & 1;
        if (kt < 15) stage(buf ^ 1, kt + 1);   // buf^1 free since kt-1 barrier
        // ---- MFMA on buf (covers the in-flight gll latency) ----
        const char* xs = (const char*)Xs[buf];
        const char* ws = (const char*)Ws[buf];
#pragma unroll
        for (int ks = 0; ks < 2; ++ks) {
            bf16x8 af = *(const bf16x8*)(xs + QSWZ(w * 16 + l16, ks * 64 + quad * 16));
#pragma unroll
            for (int nst = 0; nst < 8; ++nst) {
                bf16x8 bfr = *(const bf16x8*)(ws + QSWZ(nst * 16 + l16, ks * 64 + quad * 16));
                acc[nst] = __builtin_amdgcn_mfma_f32_16x16x32_bf16(bfr, af, acc[nst], 0, 0, 0);
            }
        }
        if (kt < 15) __syncthreads();     // drains stage(kt+1); syncs buffers
    }

    // ---- epilogue: lane holds m = l16, n = nst*16 + quad*4 + r ----
    {
        const size_t rowbase = (size_t)(mt * 128 + w * 16 + l16) * Hn;
#pragma unroll
        for (int nst = 0; nst < 8; ++nst) {
            f32x4 v = acc[nst];
            uint2 pk;
            pk.x = pkbf(v[0] * scale, v[1] * scale);
            pk.y = pkbf(v[2] * scale, v[3] * scale);
            *(uint2*)(out + rowbase + nst * 16 + quad * 4) = pk;
        }
    }
}

// ---------------------------------------------------------------------------
// Legacy fused-convert QKV (fallback if workspace too small for xb/wt).
// ---------------------------------------------------------------------------
__global__ __launch_bounds__(256)
void qkv_mfma(const float* __restrict__ x,
              const float* __restrict__ Wq,
              const float* __restrict__ Wk,
              const float* __restrict__ Wv,
              unsigned short* __restrict__ Qo,
              unsigned short* __restrict__ Ko,
              unsigned short* __restrict__ Vo) {
    const int mt = blockIdx.x;
    const int which = blockIdx.y;
    const float* W = (which == 0) ? Wq : (which == 1) ? Wk : Wv;
    unsigned short* out = (which == 0) ? Qo : (which == 1) ? Ko : Vo;
    const float scale = (which == 0) ? SCALE : 1.0f;

    __shared__ alignas(16) unsigned short Xs[128 * 72];
    __shared__ alignas(16) unsigned short Wt[128 * 72];

    const int t = threadIdx.x;
    const int w = t >> 6;
    const int lane = t & 63;
    const int quad = lane >> 4;
    const int l16 = lane & 15;

    const int xrow = t >> 1;
    const int xkc = (t & 1) * 32;
    const int ws0 = (t & 31) * 2;
    const int wd0 = (t >> 5) * 16;

    const float* xsrc0 = x + (size_t)(mt * 128 + xrow) * En + xkc;

    f32x4 acc[2][8];
#pragma unroll
    for (int mi = 0; mi < 2; ++mi)
#pragma unroll
        for (int nst = 0; nst < 8; ++nst) acc[mi][nst] = (f32x4){0.f, 0.f, 0.f, 0.f};

    float4 xpre[8], wpre[8];
    {
        const float* src = xsrc0;
#pragma unroll
        for (int i = 0; i < 8; ++i) xpre[i] = *(const float4*)(src + i * 4);
        const float* w0 = W + (size_t)ws0 * Hn + wd0;
        const float* w1 = w0 + Hn;
#pragma unroll
        for (int i = 0; i < 4; ++i) wpre[i] = *(const float4*)(w0 + i * 4);
#pragma unroll
        for (int i = 0; i < 4; ++i) wpre[4 + i] = *(const float4*)(w1 + i * 4);
    }

    for (int kt = 0; kt < 16; ++kt) {
        __syncthreads();
        {
            unsigned int u[16];
#pragma unroll
            for (int i = 0; i < 8; ++i) {
                u[2 * i]     = pkbf(xpre[i].x, xpre[i].y);
                u[2 * i + 1] = pkbf(xpre[i].z, xpre[i].w);
            }
#pragma unroll
            for (int i = 0; i < 4; ++i)
                *(uint4*)&Xs[xrow * 72 + xkc + i * 8] = ((const uint4*)u)[i];

            const float* ax = (const float*)&wpre[0];
            const float* bx = (const float*)&wpre[4];
#pragma unroll
            for (int dd = 0; dd < 16; ++dd)
                *(unsigned int*)&Wt[(wd0 + dd) * 72 + ws0] = pkbf(ax[dd], bx[dd]);
        }
        if (kt < 15) {
            const float* src = xsrc0 + (kt + 1) * 64;
#pragma unroll
            for (int i = 0; i < 8; ++i) xpre[i] = *(const float4*)(src + i * 4);
            const float* w0 = W + (size_t)((kt + 1) * 64 + ws0) * Hn + wd0;
            const float* w1 = w0 + Hn;
#pragma unroll
            for (int i = 0; i < 4; ++i) wpre[i] = *(const float4*)(w0 + i * 4);
#pragma unroll
            for (int i = 0; i < 4; ++i) wpre[4 + i] = *(const float4*)(w1 + i * 4);
        }
        __syncthreads();

#pragma unroll
        for (int ks = 0; ks < 2; ++ks) {
            bf16x8 af[2];
#pragma unroll
            for (int mi = 0; mi < 2; ++mi)
                af[mi] = *(const bf16x8*)&Xs[(w * 32 + mi * 16 + l16) * 72 + ks * 32 + quad * 8];
#pragma unroll
            for (int nst = 0; nst < 8; ++nst) {
                bf16x8 bfr = *(const bf16x8*)&Wt[(nst * 16 + l16) * 72 + ks * 32 + quad * 8];
                acc[0][nst] = __builtin_amdgcn_mfma_f32_16x16x32_bf16(bfr, af[0], acc[0][nst], 0, 0, 0);
                acc[1][nst] = __builtin_amdgcn_mfma_f32_16x16x32_bf16(bfr, af[1], acc[1][nst], 0, 0, 0);
            }
        }
    }

#pragma unroll
    for (int mi = 0; mi < 2; ++mi) {
        const size_t rowbase = (size_t)(mt * 128 + w * 32 + mi * 16 + l16) * Hn;
#pragma unroll
        for (int nst = 0; nst < 8; ++nst) {
            f32x4 v = acc[mi][nst];
            uint2 pk;
            pk.x = pkbf(v[0] * scale, v[1] * scale);
            pk.y = pkbf(v[2] * scale, v[3] * scale);
            *(uint2*)(out + rowbase + nst * 16 + quad * 4) = pk;
        }
    }
}

// ---------------------------------------------------------------------------
// MFMA flash attention v6 (verified R8/R10 optimum): split-K z=2.
// Probed and rejected: +regs (R1/R9: spill), -occupancy (R2/R6), fewer
// waves (R5), z=4 (R11: per-block fixed costs scale with z -- partial
// stores/Q-staging doubled, +9us). z=2 is the interior optimum.
// ---------------------------------------------------------------------------
#define KSWZ(r, c) (((r) << 8) + ((c) ^ (((r) & 7) << 4)))  // 256B rows (K/Q)
#define VSWZ(r, c) (((r) << 7) + ((c) ^ (((r) & 7) << 4)))  // 128B rows (V/P)

__global__ __launch_bounds__(512, 4)
void flash_mfma(const unsigned short* __restrict__ Qb,
                const unsigned short* __restrict__ Kb,
                const unsigned short* __restrict__ Vb,
                float* __restrict__ out,
                float* __restrict__ Up,      // [2][Bn*Tn][Hn] partials (split)
                float2* __restrict__ MLp) {  // [2][Bn*Tn] (m, l) (split)
    const int b = blockIdx.x;                     // batch
    const int bx = blockIdx.y;
    const int qt = (bx < 32) ? (63 - bx) : (bx - 32);
    const int z = blockIdx.z;
    const bool split = (gridDim.z == 2);
    const int h0 = (qt + 2) >> 1;                 // kv tiles in half 0
    const int lo = (split && z) ? h0 : 0;
    const int hi = split ? (z ? (qt + 1) : h0) : (qt + 1);
    const int R = hi - lo;                        // block-uniform
    const int t = threadIdx.x;
    const int w = t >> 6;                         // 0..7
    const int g = w >> 2;                         // kv-parity group (0=even,1=odd)
    const int rg = w & 3;                         // q row-group / group-local wave
    const int lane = t & 63;
    const int quad = lane >> 4;
    const int l16 = lane & 15;
    const int t256 = t & 255;                     // group-local thread id

    extern __shared__ unsigned short pool[];      // 40960 shorts = 80 KB
    char* const poolb = (char*)pool;
    char* const Kg = poolb + g * 16384;           // [64][128] bf16, swizzled
    char* const Vg = poolb + 32768 + g * 16384;   // [128][64] bf16 (V^T), swizzled
    char* const Pw = poolb + 65536 + w * 2048;    // per-wave [16][64] bf16, swizzled
    float* const Os = (float*)poolb;              // [64][132] f32 (epilogue overlay)
    float* const Ex = (float*)(poolb + 40960);    // [4][16][128] f32 (combine overlay)
    float* const Em = (float*)(poolb + 73728);    // [4][16] partial m
    float* const El = Em + 64;                    // [4][16] partial l

    const size_t gbase = (size_t)b * ((size_t)Tn * Hn);
    const unsigned short* kbase = Kb + gbase;
    const unsigned short* vbase = Vb + gbase;

    // staging coords
    const int l_hi = lane >> 4;                   // 0..3
    const int cpr = (lane & 15) * 16;             // byte col, pre-swizzle (Q/K gll)
    const int vs0 = (t256 & 31) * 2;              // V transpose-pack coords
    const int vd0 = (t256 >> 5) * 16;

    // ---- prefetch this group's V tile (kt = lo + g) ----
    uint4 vra, vrb, vrc, vrd;
    if (lo + g < hi) {
        const unsigned short* vsrc = vbase + (size_t)((lo + g) * 64) * Hn;
        vra = *(const uint4*)&vsrc[vs0 * 128 + vd0];
        vrb = *(const uint4*)&vsrc[vs0 * 128 + vd0 + 8];
        vrc = *(const uint4*)&vsrc[(vs0 + 1) * 128 + vd0];
        vrd = *(const uint4*)&vsrc[(vs0 + 1) * 128 + vd0 + 8];
    }

    // ---- stage Q tile (into group-0 K region) via global_load_lds ----
    {
        const unsigned short* qsrc = Qb + gbase + (size_t)(qt * 64) * Hn;
#pragma unroll
        for (int i = 0; i < 2; ++i) {
            const int row = w * 8 + i * 4 + l_hi;
            const int scol = cpr ^ ((row & 7) << 4);
            gll16(qsrc + row * 128 + (scol >> 1),
                  (unsigned short*)(poolb + w * 2048 + i * 1024));
        }
    }
    __syncthreads();

    // hoist Q B-frags: lane holds Q[q=l16 of row-group rg][d=ks*32+quad*8+j]
    bf16x8 qf[4];
#pragma unroll
    for (int ks = 0; ks < 4; ++ks)
        qf[ks] = *(const bf16x8*)(poolb + KSWZ(rg * 16 + l16, ks * 64 + quad * 16));

    f32x4 acc_o[8];
#pragma unroll
    for (int i = 0; i < 8; ++i) acc_o[i] = (f32x4){0.f, 0.f, 0.f, 0.f};
    float m_run = -1e30f, l_run = 0.f;

    const int n = (R + 1) >> 1;                   // group-0 trip count (>= group-1)
    for (int it = 0; it < n; ++it) {
        const int kt = lo + 2 * it + g;
        const bool active = (kt < hi);
        __syncthreads();                          // prev compute done; Kg/Vg free
        if (active) {
            // ---- K: direct global->LDS, pre-swizzled source, 4 instrs/wave
            const unsigned short* ktile = kbase + (size_t)(kt * 64) * Hn;
#pragma unroll
            for (int i = 0; i < 4; ++i) {
                const int row = rg * 16 + i * 4 + l_hi;
                const int scol = cpr ^ ((row & 7) << 4);
                gll16(ktile + row * 128 + (scol >> 1),
                      (unsigned short*)(Kg + rg * 4096 + i * 1024));
            }
            // ---- V: staged regs -> LDS transpose-pack ----
            const unsigned short* pa = (const unsigned short*)&vra;
            const unsigned short* pb = (const unsigned short*)&vrb;
            const unsigned short* pc = (const unsigned short*)&vrc;
            const unsigned short* pd = (const unsigned short*)&vrd;
#pragma unroll
            for (int dd = 0; dd < 8; ++dd)
                *(unsigned int*)(Vg + VSWZ(vd0 + dd, vs0 * 2)) =
                    (unsigned int)pa[dd] | ((unsigned int)pc[dd] << 16);
#pragma unroll
            for (int dd = 0; dd < 8; ++dd)
                *(unsigned int*)(Vg + VSWZ(vd0 + 8 + dd, vs0 * 2)) =
                    (unsigned int)pb[dd] | ((unsigned int)pd[dd] << 16);
        }
        __syncthreads();                          // drains K gll + V ds_writes
        // ---- issue next V loads AFTER barrier: drain lands next round ----
        if (kt + 2 < hi) {
            const unsigned short* vsrc = vbase + (size_t)((kt + 2) * 64) * Hn;
            vra = *(const uint4*)&vsrc[vs0 * 128 + vd0];
            vrb = *(const uint4*)&vsrc[vs0 * 128 + vd0 + 8];
            vrc = *(const uint4*)&vsrc[(vs0 + 1) * 128 + vd0];
            vrd = *(const uint4*)&vsrc[(vs0 + 1) * 128 + vd0 + 8];
        }
        if (!active) continue;                    // barriers done; skip compute

        const bool diag = (kt == qt);
        // S^T = K.Q^T ; lane holds S[q=l16][s=st*16+quad*4+r]
        f32x4 sa[4];
#pragma unroll
        for (int st = 0; st < 4; ++st) {
            if (diag && st > rg) {
                sa[st] = (f32x4){-1e30f, -1e30f, -1e30f, -1e30f};  // fully masked
            } else {
                f32x4 c = (f32x4){0.f, 0.f, 0.f, 0.f};
#pragma unroll
                for (int ks = 0; ks < 4; ++ks) {
                    bf16x8 kf = *(const bf16x8*)(Kg + KSWZ(st * 16 + l16, ks * 64 + quad * 16));
                    c = __builtin_amdgcn_mfma_f32_16x16x32_bf16(kf, qf[ks], c, 0, 0, 0);
                }
                if (diag && st == rg) {
#pragma unroll
                    for (int r = 0; r < 4; ++r)
                        if (quad * 4 + r > l16) c[r] = -1e30f;
                }
                sa[st] = c;
            }
        }

        // row max (max3-friendly tree), replicated across the 4 quads
        float t0 = fmaxf(fmaxf(sa[0][0], sa[0][1]), fmaxf(sa[0][2], sa[0][3]));
        float t1 = fmaxf(fmaxf(sa[1][0], sa[1][1]), fmaxf(sa[1][2], sa[1][3]));
        float t2 = fmaxf(fmaxf(sa[2][0], sa[2][1]), fmaxf(sa[2][2], sa[2][3]));
        float t3 = fmaxf(fmaxf(sa[3][0], sa[3][1]), fmaxf(sa[3][2], sa[3][3]));
        float mloc = fmaxf(fmaxf(t0, t1), fmaxf(t2, t3));
        mloc = fmaxf(mloc, __shfl_xor(mloc, 16));
        mloc = fmaxf(mloc, __shfl_xor(mloc, 32));

        // T13 defer-max: skip rescale when no row grew past m_run+8.
        if (!__all(mloc <= m_run + 8.0f)) {
            const float m_new = fmaxf(m_run, mloc);
            const float alpha = __expf(m_run - m_new);
            l_run *= alpha;
#pragma unroll
            for (int i = 0; i < 8; ++i) acc_o[i] *= alpha;
            m_run = m_new;
        }
        float lsum = 0.f;
#pragma unroll
        for (int st = 0; st < 4; ++st)
#pragma unroll
            for (int r = 0; r < 4; ++r) {
                const float e = __expf(sa[st][r] - m_run);
                sa[st][r] = e;                    // exp in place
                lsum += e;
            }
        lsum += __shfl_xor(lsum, 16);
        lsum += __shfl_xor(lsum, 32);
        l_run += lsum;

        // P (C-layout) -> per-wave LDS -> P^T B-frags (same-wave, no barrier)
#pragma unroll
        for (int st = 0; st < 4; ++st) {
            uint2 pk;
            pk.x = pkbf(sa[st][0], sa[st][1]);
            pk.y = pkbf(sa[st][2], sa[st][3]);
            *(uint2*)(Pw + VSWZ(l16, st * 32 + quad * 8)) = pk;
        }
        bf16x8 pf0 = *(const bf16x8*)(Pw + VSWZ(l16, quad * 16));
        bf16x8 pf1 = *(const bf16x8*)(Pw + VSWZ(l16, 64 + quad * 16));

        // O^T += V^T . P^T
#pragma unroll
        for (int dt = 0; dt < 8; ++dt) {
            bf16x8 vf0 = *(const bf16x8*)(Vg + VSWZ(dt * 16 + l16, quad * 16));
            acc_o[dt] = __builtin_amdgcn_mfma_f32_16x16x32_bf16(vf0, pf0, acc_o[dt], 0, 0, 0);
            bf16x8 vf1 = *(const bf16x8*)(Vg + VSWZ(dt * 16 + l16, 64 + quad * 16));
            acc_o[dt] = __builtin_amdgcn_mfma_f32_16x16x32_bf16(vf1, pf1, acc_o[dt], 0, 0, 0);
        }
    }

    // ---- in-block flash combine: group 1 publishes (m,l,O); group 0 merges ----
    __syncthreads();
    if (g == 1) {
        float* dst = Ex + (rg * 16 + l16) * 128;
#pragma unroll
        for (int dt = 0; dt < 8; ++dt)
            *(f32x4*)&dst[dt * 16 + quad * 4] = acc_o[dt];
        if (quad == 0) {
            Em[rg * 16 + l16] = m_run;
            El[rg * 16 + l16] = l_run;
        }
    }
    __syncthreads();
    if (g == 0) {
        const float* src = Ex + (rg * 16 + l16) * 128;
        const float m2 = Em[rg * 16 + l16];
        const float l2 = El[rg * 16 + l16];
        const float ms = fmaxf(m_run, m2);
        const float a1 = __expf(m_run - ms);
        const float a2 = __expf(m2 - ms);
        const float den = l_run * a1 + l2 * a2;
        const float scl = split ? 1.f : (1.f / den);
#pragma unroll
        for (int dt = 0; dt < 8; ++dt) {
            f32x4 o2 = *(const f32x4*)&src[dt * 16 + quad * 4];
            f32x4 v = (acc_o[dt] * a1 + o2 * a2) * scl;
            *(f32x4*)&Os[(rg * 16 + l16) * 132 + dt * 16 + quad * 4] = v;
        }
        if (split && quad == 0)
            MLp[(size_t)z * (Bn * Tn) + (size_t)b * Tn + qt * 64 + rg * 16 + l16] =
                make_float2(ms, den);
    }
    __syncthreads();
    // coalesced fp32 stores, all 512 threads
    float* dst = split
        ? (Up + ((size_t)z * Bn * Tn + (size_t)b * Tn + (size_t)qt * 64) * Hn)
        : (out + gbase + (size_t)(qt * 64) * Hn);
#pragma unroll
    for (int i = 0; i < 4; ++i) {
        const int idx = (t + i * 512) * 4;
        const int row = idx >> 7, col = idx & 127;
        *(float4*)&dst[row * 128 + col] = *(const float4*)&Os[row * 132 + col];
    }
}

// ---------------------------------------------------------------------------
// fcomb: merge the two split-K partials. 1,048,576 f32x4 quads, 4096 blocks.
// out = (a0*U0 + a1*U1) / (a0*l0 + a1*l1), a_i = exp(m_i - max(m0,m1)).
// ---------------------------------------------------------------------------
__global__ __launch_bounds__(256)
void fcomb(const float* __restrict__ U, const float2* __restrict__ ml,
           float* __restrict__ out) {
    const size_t i = (size_t)blockIdx.x * 256 + threadIdx.x;   // quad index
    const size_t grow = i >> 5;                                // global q-row
    const int c4 = (int)(i & 31) * 4;
    const float2 p0 = ml[grow];
    const float2 p1 = ml[(size_t)Bn * Tn + grow];
    const float ms = fmaxf(p0.x, p1.x);
    const float a0 = __expf(p0.x - ms);
    const float a1 = __expf(p1.x - ms);
    const float inv = 1.f / (a0 * p0.y + a1 * p1.y);
    const f32x4 u0 = *(const f32x4*)&U[grow * Hn + c4];
    const f32x4 u1 = *(const f32x4*)&U[(size_t)Bn * Tn * Hn + grow * Hn + c4];
    f32x4 v = (u0 * a0 + u1 * a1) * inv;
    *(f32x4*)&out[grow * Hn + c4] = v;
}

// ---------------------------------------------------------------------------
extern "C" void kernel_launch(void* const* d_in, const int* in_sizes, int n_in,
                              void* d_out, int out_size, void* d_ws, size_t ws_size,
                              hipStream_t stream) {
    const float* x  = (const float*)d_in[0];
    const float* Wq = (const float*)d_in[1];
    const float* Wk = (const float*)d_in[2];
    const float* Wv = (const float*)d_in[3];
    float* o = (float*)d_out;            // output fp32 (verified round 4)

    const size_t qkvb = (size_t)Bn * Tn * Hn;          // 4,194,304 elems
    unsigned short* Qb = (unsigned short*)d_ws;        // (B*T, H) bf16
    unsigned short* Kb = Qb + qkvb;
    unsigned short* Vb = Kb + qkvb;
    unsigned short* xbf = Vb + qkvb;                   // (B*T, E) bf16, 67 MB
    unsigned short* wt3 = xbf + (size_t)Bn * Tn * En;  // 3 x (H, E) bf16

    // split-K partials overlay the xbf region (dead after qkv2):
    // U = 2*Bn*Tn*Hn f32 (33.5 MB) + ML = 2*Bn*Tn float2 (0.5 MB) < 67 MB.
    float* Up = (float*)xbf;
    float2* MLp = (float2*)((char*)xbf + (size_t)2 * Bn * Tn * Hn * sizeof(float));

    const size_t ws_need = (3 * qkvb + (size_t)Bn * Tn * En + 3 * (size_t)Hn * En)
                           * sizeof(unsigned short);

    static bool attr_done = false;
    if (!attr_done) {
        hipFuncSetAttribute((const void*)flash_mfma,
                            hipFuncAttributeMaxDynamicSharedMemorySize, 81920);
        attr_done = true;
    }

    if (ws_size >= ws_need) {
        cvtall<<<8216, 256, 0, stream>>>(x, xbf, Wq, Wk, Wv, wt3);
        qkv2<<<dim3(256, 3), 512, 0, stream>>>(xbf, wt3, Qb, Kb, Vb);
        flash_mfma<<<dim3(8, 64, 2), 512, 81920, stream>>>(Qb, Kb, Vb, o, Up, MLp);
        fcomb<<<4096, 256, 0, stream>>>(Up, MLp, o);
    } else {
        qkv_mfma<<<dim3(256, 3), 256, 0, stream>>>(x, Wq, Wk, Wv, Qb, Kb, Vb);
        flash_mfma<<<dim3(8, 64, 1), 512, 81920, stream>>>(Qb, Kb, Vb, o,
                                                           nullptr, nullptr);
    }
}

// Round 13
// 334.823 us; speedup vs baseline: 1.0560x; 1.0127x over previous
//
#include <hip/hip_runtime.h>
#include <hip/hip_bf16.h>
#include <stdint.h>

#define Bn 8
#define Tn 4096
#define En 1024
#define Hn 128
#define SCALE 0.08838834764831845f  // 1/sqrt(128)

typedef __attribute__((ext_vector_type(8))) short bf16x8;
typedef __attribute__((ext_vector_type(4))) float f32x4;

__device__ __forceinline__ float bf2f(unsigned short v) {
    return __uint_as_float(((unsigned int)v) << 16);
}
// RNE pack of two fp32 -> packed bf16x2 (v_cvt_pk_bf16_f32 on gfx950)
__device__ __forceinline__ unsigned int pkbf(float a, float b) {
    __hip_bfloat162 h = __float22bfloat162_rn(make_float2(a, b));
    union { __hip_bfloat162 h2; unsigned int u; } cv;
    cv.h2 = h;
    return cv.u;
}

// async global->LDS, 16B per lane, LDS dest = wave-uniform base + lane*16
__device__ __forceinline__ void gll16(const unsigned short* g, unsigned short* l) {
    __builtin_amdgcn_global_load_lds(
        (const __attribute__((address_space(1))) void*)g,
        (__attribute__((address_space(3))) void*)l, 16, 0, 0);
}

// ---------------------------------------------------------------------------
// cvtall: fused xcvt + wcvt (verified R11/R12).
// blocks [0,8192): x fp32 -> bf16 streaming, 16 elems/thread.
// blocks [8192,8216): W (1024x128 fp32) -> Wt (128x1024 bf16, transposed).
// ---------------------------------------------------------------------------
__global__ __launch_bounds__(256)
void cvtall(const float* __restrict__ x, unsigned short* __restrict__ xb,
            const float* __restrict__ Wq, const float* __restrict__ Wk,
            const float* __restrict__ Wv, unsigned short* __restrict__ wt3) {
    __shared__ unsigned short wl[128 * 132];  // [k][n] bf16, pad 132 (wcvt only)
    const int t = threadIdx.x;
    if (blockIdx.x < 8192) {
        const size_t i = ((size_t)blockIdx.x * 256 + t) * 16;
        const float4* src = (const float4*)(x + i);
        float4 a = src[0], b = src[1], c = src[2], d = src[3];
        uint4 o0, o1;
        o0.x = pkbf(a.x, a.y); o0.y = pkbf(a.z, a.w);
        o0.z = pkbf(b.x, b.y); o0.w = pkbf(b.z, b.w);
        o1.x = pkbf(c.x, c.y); o1.y = pkbf(c.z, c.w);
        o1.z = pkbf(d.x, d.y); o1.w = pkbf(d.z, d.w);
        *(uint4*)(xb + i) = o0;
        *(uint4*)(xb + i + 8) = o1;
        return;
    }
    const int bid2 = blockIdx.x - 8192;   // 0..23
    const int which = bid2 >> 3;
    const int k0 = (bid2 & 7) * 128;
    const float* W = (which == 0) ? Wq : (which == 1) ? Wk : Wv;
    unsigned short* wt = wt3 + (size_t)which * 131072;
#pragma unroll
    for (int i = 0; i < 16; ++i) {
        const int idx = t + i * 256;          // < 4096
        const int k = idx >> 5, c4 = idx & 31;
        float4 v = *(const float4*)&W[(size_t)(k0 + k) * Hn + c4 * 4];
        uint2 p;
        p.x = pkbf(v.x, v.y);
        p.y = pkbf(v.z, v.w);
        *(uint2*)&wl[k * 132 + c4 * 4] = p;
    }
    __syncthreads();
#pragma unroll
    for (int j = 0; j < 32; ++j) {
        const int idx = t + j * 256;          // < 8192
        const int n = idx >> 6, kp = idx & 63;
        unsigned int u = (unsigned int)wl[(2 * kp) * 132 + n] |
                         ((unsigned int)wl[(2 * kp + 1) * 132 + n] << 16);
        *(unsigned int*)&wt[(size_t)n * 1024 + k0 + 2 * kp] = u;
    }
}

// ---------------------------------------------------------------------------
// qkv2: all-bf16 QKV GEMM, 8 waves/block (verified round 7).
// ---------------------------------------------------------------------------
#define QSWZ(r, c) (((r) << 7) + ((c) ^ (((r) & 7) << 4)))  // 128B rows, byte addr

__global__ __launch_bounds__(512, 4)
void qkv2(const unsigned short* __restrict__ xb,
          const unsigned short* __restrict__ wt3,
          unsigned short* __restrict__ Qo,
          unsigned short* __restrict__ Ko,
          unsigned short* __restrict__ Vo) {
    const int mt = blockIdx.x;
    const int which = blockIdx.y;
    const unsigned short* wt = wt3 + (size_t)which * 131072;
    unsigned short* out = (which == 0) ? Qo : (which == 1) ? Ko : Vo;
    const float scale = (which == 0) ? SCALE : 1.0f;

    __shared__ alignas(16) unsigned short Xs[2][128 * 64];  // 32 KB
    __shared__ alignas(16) unsigned short Ws[2][128 * 64];  // 32 KB

    const int t = threadIdx.x;
    const int w = t >> 6;                 // 0..7
    const int lane = t & 63;
    const int quad = lane >> 4;
    const int l16 = lane & 15;
    const int r8 = lane >> 3;             // lane's row within 8-row gll slab
    const int cb = lane & 7;              // lane's 16B col-block

    const unsigned short* xtile = xb + (size_t)(mt * 128) * En;

    f32x4 acc[8];
#pragma unroll
    for (int nst = 0; nst < 8; ++nst) acc[nst] = (f32x4){0.f, 0.f, 0.f, 0.f};

    // stage tile kt into buffer buf: 2 gll16 for X + 2 for W per thread
    auto stage = [&](int buf, int kt) {
#pragma unroll
        for (int i = 0; i < 2; ++i) {
            const int row = w * 16 + i * 8 + r8;      // row&7 == r8
            gll16(xtile + (size_t)row * En + kt * 64 + ((cb ^ (row & 7)) * 8),
                  &Xs[buf][(w * 16 + i * 8) * 64]);
        }
#pragma unroll
        for (int i = 0; i < 2; ++i) {
            const int row = w * 16 + i * 8 + r8;
            gll16(wt + (size_t)row * 1024 + kt * 64 + ((cb ^ (row & 7)) * 8),
                  &Ws[buf][(w * 16 + i * 8) * 64]);
        }
    };

    stage(0, 0);
    __syncthreads();                      // drains prologue gll

    for (int kt = 0; kt < 16; ++kt) {
        const int buf = kt & 1;
        if (kt < 15) stage(buf ^ 1, kt + 1);   // buf^1 free since kt-1 barrier
        // ---- MFMA on buf (covers the in-flight gll latency) ----
        const char* xs = (const char*)Xs[buf];
        const char* ws = (const char*)Ws[buf];
#pragma unroll
        for (int ks = 0; ks < 2; ++ks) {
            bf16x8 af = *(const bf16x8*)(xs + QSWZ(w * 16 + l16, ks * 64 + quad * 16));
#pragma unroll
            for (int nst = 0; nst < 8; ++nst) {
                bf16x8 bfr = *(const bf16x8*)(ws + QSWZ(nst * 16 + l16, ks * 64 + quad * 16));
                acc[nst] = __builtin_amdgcn_mfma_f32_16x16x32_bf16(bfr, af, acc[nst], 0, 0, 0);
            }
        }
        if (kt < 15) __syncthreads();     // drains stage(kt+1); syncs buffers
    }

    // ---- epilogue: lane holds m = l16, n = nst*16 + quad*4 + r ----
    {
        const size_t rowbase = (size_t)(mt * 128 + w * 16 + l16) * Hn;
#pragma unroll
        for (int nst = 0; nst < 8; ++nst) {
            f32x4 v = acc[nst];
            uint2 pk;
            pk.x = pkbf(v[0] * scale, v[1] * scale);
            pk.y = pkbf(v[2] * scale, v[3] * scale);
            *(uint2*)(out + rowbase + nst * 16 + quad * 4) = pk;
        }
    }
}

// ---------------------------------------------------------------------------
// Legacy fused-convert QKV (fallback if workspace too small for xb/wt).
// ---------------------------------------------------------------------------
__global__ __launch_bounds__(256)
void qkv_mfma(const float* __restrict__ x,
              const float* __restrict__ Wq,
              const float* __restrict__ Wk,
              const float* __restrict__ Wv,
              unsigned short* __restrict__ Qo,
              unsigned short* __restrict__ Ko,
              unsigned short* __restrict__ Vo) {
    const int mt = blockIdx.x;
    const int which = blockIdx.y;
    const float* W = (which == 0) ? Wq : (which == 1) ? Wk : Wv;
    unsigned short* out = (which == 0) ? Qo : (which == 1) ? Ko : Vo;
    const float scale = (which == 0) ? SCALE : 1.0f;

    __shared__ alignas(16) unsigned short Xs[128 * 72];
    __shared__ alignas(16) unsigned short Wt[128 * 72];

    const int t = threadIdx.x;
    const int w = t >> 6;
    const int lane = t & 63;
    const int quad = lane >> 4;
    const int l16 = lane & 15;

    const int xrow = t >> 1;
    const int xkc = (t & 1) * 32;
    const int ws0 = (t & 31) * 2;
    const int wd0 = (t >> 5) * 16;

    const float* xsrc0 = x + (size_t)(mt * 128 + xrow) * En + xkc;

    f32x4 acc[2][8];
#pragma unroll
    for (int mi = 0; mi < 2; ++mi)
#pragma unroll
        for (int nst = 0; nst < 8; ++nst) acc[mi][nst] = (f32x4){0.f, 0.f, 0.f, 0.f};

    float4 xpre[8], wpre[8];
    {
        const float* src = xsrc0;
#pragma unroll
        for (int i = 0; i < 8; ++i) xpre[i] = *(const float4*)(src + i * 4);
        const float* w0 = W + (size_t)ws0 * Hn + wd0;
        const float* w1 = w0 + Hn;
#pragma unroll
        for (int i = 0; i < 4; ++i) wpre[i] = *(const float4*)(w0 + i * 4);
#pragma unroll
        for (int i = 0; i < 4; ++i) wpre[4 + i] = *(const float4*)(w1 + i * 4);
    }

    for (int kt = 0; kt < 16; ++kt) {
        __syncthreads();
        {
            unsigned int u[16];
#pragma unroll
            for (int i = 0; i < 8; ++i) {
                u[2 * i]     = pkbf(xpre[i].x, xpre[i].y);
                u[2 * i + 1] = pkbf(xpre[i].z, xpre[i].w);
            }
#pragma unroll
            for (int i = 0; i < 4; ++i)
                *(uint4*)&Xs[xrow * 72 + xkc + i * 8] = ((const uint4*)u)[i];

            const float* ax = (const float*)&wpre[0];
            const float* bx = (const float*)&wpre[4];
#pragma unroll
            for (int dd = 0; dd < 16; ++dd)
                *(unsigned int*)&Wt[(wd0 + dd) * 72 + ws0] = pkbf(ax[dd], bx[dd]);
        }
        if (kt < 15) {
            const float* src = xsrc0 + (kt + 1) * 64;
#pragma unroll
            for (int i = 0; i < 8; ++i) xpre[i] = *(const float4*)(src + i * 4);
            const float* w0 = W + (size_t)((kt + 1) * 64 + ws0) * Hn + wd0;
            const float* w1 = w0 + Hn;
#pragma unroll
            for (int i = 0; i < 4; ++i) wpre[i] = *(const float4*)(w0 + i * 4);
#pragma unroll
            for (int i = 0; i < 4; ++i) wpre[4 + i] = *(const float4*)(w1 + i * 4);
        }
        __syncthreads();

#pragma unroll
        for (int ks = 0; ks < 2; ++ks) {
            bf16x8 af[2];
#pragma unroll
            for (int mi = 0; mi < 2; ++mi)
                af[mi] = *(const bf16x8*)&Xs[(w * 32 + mi * 16 + l16) * 72 + ks * 32 + quad * 8];
#pragma unroll
            for (int nst = 0; nst < 8; ++nst) {
                bf16x8 bfr = *(const bf16x8*)&Wt[(nst * 16 + l16) * 72 + ks * 32 + quad * 8];
                acc[0][nst] = __builtin_amdgcn_mfma_f32_16x16x32_bf16(bfr, af[0], acc[0][nst], 0, 0, 0);
                acc[1][nst] = __builtin_amdgcn_mfma_f32_16x16x32_bf16(bfr, af[1], acc[1][nst], 0, 0, 0);
            }
        }
    }

#pragma unroll
    for (int mi = 0; mi < 2; ++mi) {
        const size_t rowbase = (size_t)(mt * 128 + w * 32 + mi * 16 + l16) * Hn;
#pragma unroll
        for (int nst = 0; nst < 8; ++nst) {
            f32x4 v = acc[mi][nst];
            uint2 pk;
            pk.x = pkbf(v[0] * scale, v[1] * scale);
            pk.y = pkbf(v[2] * scale, v[3] * scale);
            *(uint2*)(out + rowbase + nst * 16 + quad * 4) = pk;
        }
    }
}

// ---------------------------------------------------------------------------
// MFMA flash attention v6.2 = verified R12 (z=2 split-K) + two zero-register
// micro-edits: (a) T5 s_setprio around MFMA clusters -- untested on THIS
// structure (R2's negative was confounded with an occupancy collapse; m191
// shows +4-7% for attn with independent co-resident blocks, which is what
// split-K gives: 2 independent blocks/CU at different phases); (b) pure-LPT
// qt = 63-bx (the (c,63-c) pairing rationale died when split-K equalized
// block sizes). Tripwires: VGPR 64, WRITE_SIZE 34.9 MB.
// ---------------------------------------------------------------------------
#define KSWZ(r, c) (((r) << 8) + ((c) ^ (((r) & 7) << 4)))  // 256B rows (K/Q)
#define VSWZ(r, c) (((r) << 7) + ((c) ^ (((r) & 7) << 4)))  // 128B rows (V/P)

__global__ __launch_bounds__(512, 4)
void flash_mfma(const unsigned short* __restrict__ Qb,
                const unsigned short* __restrict__ Kb,
                const unsigned short* __restrict__ Vb,
                float* __restrict__ out,
                float* __restrict__ Up,      // [2][Bn*Tn][Hn] partials (split)
                float2* __restrict__ MLp) {  // [2][Bn*Tn] (m, l) (split)
    const int b = blockIdx.x;                     // batch
    const int qt = 63 - blockIdx.y;               // pure LPT: heavy tiles first
    const int z = blockIdx.z;
    const bool split = (gridDim.z == 2);
    const int h0 = (qt + 2) >> 1;                 // kv tiles in half 0
    const int lo = (split && z) ? h0 : 0;
    const int hi = split ? (z ? (qt + 1) : h0) : (qt + 1);
    const int R = hi - lo;                        // block-uniform
    const int t = threadIdx.x;
    const int w = t >> 6;                         // 0..7
    const int g = w >> 2;                         // kv-parity group (0=even,1=odd)
    const int rg = w & 3;                         // q row-group / group-local wave
    const int lane = t & 63;
    const int quad = lane >> 4;
    const int l16 = lane & 15;
    const int t256 = t & 255;                     // group-local thread id

    extern __shared__ unsigned short pool[];      // 40960 shorts = 80 KB
    char* const poolb = (char*)pool;
    char* const Kg = poolb + g * 16384;           // [64][128] bf16, swizzled
    char* const Vg = poolb + 32768 + g * 16384;   // [128][64] bf16 (V^T), swizzled
    char* const Pw = poolb + 65536 + w * 2048;    // per-wave [16][64] bf16, swizzled
    float* const Os = (float*)poolb;              // [64][132] f32 (epilogue overlay)
    float* const Ex = (float*)(poolb + 40960);    // [4][16][128] f32 (combine overlay)
    float* const Em = (float*)(poolb + 73728);    // [4][16] partial m
    float* const El = Em + 64;                    // [4][16] partial l

    const size_t gbase = (size_t)b * ((size_t)Tn * Hn);
    const unsigned short* kbase = Kb + gbase;
    const unsigned short* vbase = Vb + gbase;

    // staging coords
    const int l_hi = lane >> 4;                   // 0..3
    const int cpr = (lane & 15) * 16;             // byte col, pre-swizzle (Q/K gll)
    const int vs0 = (t256 & 31) * 2;              // V transpose-pack coords
    const int vd0 = (t256 >> 5) * 16;

    // ---- prefetch this group's V tile (kt = lo + g) ----
    uint4 vra, vrb, vrc, vrd;
    if (lo + g < hi) {
        const unsigned short* vsrc = vbase + (size_t)((lo + g) * 64) * Hn;
        vra = *(const uint4*)&vsrc[vs0 * 128 + vd0];
        vrb = *(const uint4*)&vsrc[vs0 * 128 + vd0 + 8];
        vrc = *(const uint4*)&vsrc[(vs0 + 1) * 128 + vd0];
        vrd = *(const uint4*)&vsrc[(vs0 + 1) * 128 + vd0 + 8];
    }

    // ---- stage Q tile (into group-0 K region) via global_load_lds ----
    {
        const unsigned short* qsrc = Qb + gbase + (size_t)(qt * 64) * Hn;
#pragma unroll
        for (int i = 0; i < 2; ++i) {
            const int row = w * 8 + i * 4 + l_hi;
            const int scol = cpr ^ ((row & 7) << 4);
            gll16(qsrc + row * 128 + (scol >> 1),
                  (unsigned short*)(poolb + w * 2048 + i * 1024));
        }
    }
    __syncthreads();

    // hoist Q B-frags: lane holds Q[q=l16 of row-group rg][d=ks*32+quad*8+j]
    bf16x8 qf[4];
#pragma unroll
    for (int ks = 0; ks < 4; ++ks)
        qf[ks] = *(const bf16x8*)(poolb + KSWZ(rg * 16 + l16, ks * 64 + quad * 16));

    f32x4 acc_o[8];
#pragma unroll
    for (int i = 0; i < 8; ++i) acc_o[i] = (f32x4){0.f, 0.f, 0.f, 0.f};
    float m_run = -1e30f, l_run = 0.f;

    const int n = (R + 1) >> 1;                   // group-0 trip count (>= group-1)
    for (int it = 0; it < n; ++it) {
        const int kt = lo + 2 * it + g;
        const bool active = (kt < hi);
        __syncthreads();                          // prev compute done; Kg/Vg free
        if (active) {
            // ---- K: direct global->LDS, pre-swizzled source, 4 instrs/wave
            const unsigned short* ktile = kbase + (size_t)(kt * 64) * Hn;
#pragma unroll
            for (int i = 0; i < 4; ++i) {
                const int row = rg * 16 + i * 4 + l_hi;
                const int scol = cpr ^ ((row & 7) << 4);
                gll16(ktile + row * 128 + (scol >> 1),
                      (unsigned short*)(Kg + rg * 4096 + i * 1024));
            }
            // ---- V: staged regs -> LDS transpose-pack ----
            const unsigned short* pa = (const unsigned short*)&vra;
            const unsigned short* pb = (const unsigned short*)&vrb;
            const unsigned short* pc = (const unsigned short*)&vrc;
            const unsigned short* pd = (const unsigned short*)&vrd;
#pragma unroll
            for (int dd = 0; dd < 8; ++dd)
                *(unsigned int*)(Vg + VSWZ(vd0 + dd, vs0 * 2)) =
                    (unsigned int)pa[dd] | ((unsigned int)pc[dd] << 16);
#pragma unroll
            for (int dd = 0; dd < 8; ++dd)
                *(unsigned int*)(Vg + VSWZ(vd0 + 8 + dd, vs0 * 2)) =
                    (unsigned int)pb[dd] | ((unsigned int)pd[dd] << 16);
        }
        __syncthreads();                          // drains K gll + V ds_writes
        // ---- issue next V loads AFTER barrier: drain lands next round ----
        if (kt + 2 < hi) {
            const unsigned short* vsrc = vbase + (size_t)((kt + 2) * 64) * Hn;
            vra = *(const uint4*)&vsrc[vs0 * 128 + vd0];
            vrb = *(const uint4*)&vsrc[vs0 * 128 + vd0 + 8];
            vrc = *(const uint4*)&vsrc[(vs0 + 1) * 128 + vd0];
            vrd = *(const uint4*)&vsrc[(vs0 + 1) * 128 + vd0 + 8];
        }
        if (!active) continue;                    // barriers done; skip compute

        const bool diag = (kt == qt);
        // S^T = K.Q^T ; lane holds S[q=l16][s=st*16+quad*4+r]
        f32x4 sa[4];
        __builtin_amdgcn_s_setprio(1);            // T5: favor MFMA waves
#pragma unroll
        for (int st = 0; st < 4; ++st) {
            if (diag && st > rg) {
                sa[st] = (f32x4){-1e30f, -1e30f, -1e30f, -1e30f};  // fully masked
            } else {
                f32x4 c = (f32x4){0.f, 0.f, 0.f, 0.f};
#pragma unroll
                for (int ks = 0; ks < 4; ++ks) {
                    bf16x8 kf = *(const bf16x8*)(Kg + KSWZ(st * 16 + l16, ks * 64 + quad * 16));
                    c = __builtin_amdgcn_mfma_f32_16x16x32_bf16(kf, qf[ks], c, 0, 0, 0);
                }
                if (diag && st == rg) {
#pragma unroll
                    for (int r = 0; r < 4; ++r)
                        if (quad * 4 + r > l16) c[r] = -1e30f;
                }
                sa[st] = c;
            }
        }
        __builtin_amdgcn_s_setprio(0);

        // row max (max3-friendly tree), replicated across the 4 quads
        float t0 = fmaxf(fmaxf(sa[0][0], sa[0][1]), fmaxf(sa[0][2], sa[0][3]));
        float t1 = fmaxf(fmaxf(sa[1][0], sa[1][1]), fmaxf(sa[1][2], sa[1][3]));
        float t2 = fmaxf(fmaxf(sa[2][0], sa[2][1]), fmaxf(sa[2][2], sa[2][3]));
        float t3 = fmaxf(fmaxf(sa[3][0], sa[3][1]), fmaxf(sa[3][2], sa[3][3]));
        float mloc = fmaxf(fmaxf(t0, t1), fmaxf(t2, t3));
        mloc = fmaxf(mloc, __shfl_xor(mloc, 16));
        mloc = fmaxf(mloc, __shfl_xor(mloc, 32));

        // T13 defer-max: skip rescale when no row grew past m_run+8.
        if (!__all(mloc <= m_run + 8.0f)) {
            const float m_new = fmaxf(m_run, mloc);
            const float alpha = __expf(m_run - m_new);
            l_run *= alpha;
#pragma unroll
            for (int i = 0; i < 8; ++i) acc_o[i] *= alpha;
            m_run = m_new;
        }
        float lsum = 0.f;
#pragma unroll
        for (int st = 0; st < 4; ++st)
#pragma unroll
            for (int r = 0; r < 4; ++r) {
                const float e = __expf(sa[st][r] - m_run);
                sa[st][r] = e;                    // exp in place
                lsum += e;
            }
        lsum += __shfl_xor(lsum, 16);
        lsum += __shfl_xor(lsum, 32);
        l_run += lsum;

        // P (C-layout) -> per-wave LDS -> P^T B-frags (same-wave, no barrier)
#pragma unroll
        for (int st = 0; st < 4; ++st) {
            uint2 pk;
            pk.x = pkbf(sa[st][0], sa[st][1]);
            pk.y = pkbf(sa[st][2], sa[st][3]);
            *(uint2*)(Pw + VSWZ(l16, st * 32 + quad * 8)) = pk;
        }
        bf16x8 pf0 = *(const bf16x8*)(Pw + VSWZ(l16, quad * 16));
        bf16x8 pf1 = *(const bf16x8*)(Pw + VSWZ(l16, 64 + quad * 16));

        // O^T += V^T . P^T
        __builtin_amdgcn_s_setprio(1);            // T5: favor MFMA waves
#pragma unroll
        for (int dt = 0; dt < 8; ++dt) {
            bf16x8 vf0 = *(const bf16x8*)(Vg + VSWZ(dt * 16 + l16, quad * 16));
            acc_o[dt] = __builtin_amdgcn_mfma_f32_16x16x32_bf16(vf0, pf0, acc_o[dt], 0, 0, 0);
            bf16x8 vf1 = *(const bf16x8*)(Vg + VSWZ(dt * 16 + l16, 64 + quad * 16));
            acc_o[dt] = __builtin_amdgcn_mfma_f32_16x16x32_bf16(vf1, pf1, acc_o[dt], 0, 0, 0);
        }
        __builtin_amdgcn_s_setprio(0);
    }

    // ---- in-block flash combine: group 1 publishes (m,l,O); group 0 merges ----
    __syncthreads();
    if (g == 1) {
        float* dst = Ex + (rg * 16 + l16) * 128;
#pragma unroll
        for (int dt = 0; dt < 8; ++dt)
            *(f32x4*)&dst[dt * 16 + quad * 4] = acc_o[dt];
        if (quad == 0) {
            Em[rg * 16 + l16] = m_run;
            El[rg * 16 + l16] = l_run;
        }
    }
    __syncthreads();
    if (g == 0) {
        const float* src = Ex + (rg * 16 + l16) * 128;
        const float m2 = Em[rg * 16 + l16];
        const float l2 = El[rg * 16 + l16];
        const float ms = fmaxf(m_run, m2);
        const float a1 = __expf(m_run - ms);
        const float a2 = __expf(m2 - ms);
        const float den = l_run * a1 + l2 * a2;
        const float scl = split ? 1.f : (1.f / den);
#pragma unroll
        for (int dt = 0; dt < 8; ++dt) {
            f32x4 o2 = *(const f32x4*)&src[dt * 16 + quad * 4];
            f32x4 v = (acc_o[dt] * a1 + o2 * a2) * scl;
            *(f32x4*)&Os[(rg * 16 + l16) * 132 + dt * 16 + quad * 4] = v;
        }
        if (split && quad == 0)
            MLp[(size_t)z * (Bn * Tn) + (size_t)b * Tn + qt * 64 + rg * 16 + l16] =
                make_float2(ms, den);
    }
    __syncthreads();
    // coalesced fp32 stores, all 512 threads
    float* dst = split
        ? (Up + ((size_t)z * Bn * Tn + (size_t)b * Tn + (size_t)qt * 64) * Hn)
        : (out + gbase + (size_t)(qt * 64) * Hn);
#pragma unroll
    for (int i = 0; i < 4; ++i) {
        const int idx = (t + i * 512) * 4;
        const int row = idx >> 7, col = idx & 127;
        *(float4*)&dst[row * 128 + col] = *(const float4*)&Os[row * 132 + col];
    }
}

// ---------------------------------------------------------------------------
// fcomb: merge the two split-K partials. 1,048,576 f32x4 quads, 4096 blocks.
// out = (a0*U0 + a1*U1) / (a0*l0 + a1*l1), a_i = exp(m_i - max(m0,m1)).
// ---------------------------------------------------------------------------
__global__ __launch_bounds__(256)
void fcomb(const float* __restrict__ U, const float2* __restrict__ ml,
           float* __restrict__ out) {
    const size_t i = (size_t)blockIdx.x * 256 + threadIdx.x;   // quad index
    const size_t grow = i >> 5;                                // global q-row
    const int c4 = (int)(i & 31) * 4;
    const float2 p0 = ml[grow];
    const float2 p1 = ml[(size_t)Bn * Tn + grow];
    const float ms = fmaxf(p0.x, p1.x);
    const float a0 = __expf(p0.x - ms);
    const float a1 = __expf(p1.x - ms);
    const float inv = 1.f / (a0 * p0.y + a1 * p1.y);
    const f32x4 u0 = *(const f32x4*)&U[grow * Hn + c4];
    const f32x4 u1 = *(const f32x4*)&U[(size_t)Bn * Tn * Hn + grow * Hn + c4];
    f32x4 v = (u0 * a0 + u1 * a1) * inv;
    *(f32x4*)&out[grow * Hn + c4] = v;
}

// ---------------------------------------------------------------------------
extern "C" void kernel_launch(void* const* d_in, const int* in_sizes, int n_in,
                              void* d_out, int out_size, void* d_ws, size_t ws_size,
                              hipStream_t stream) {
    const float* x  = (const float*)d_in[0];
    const float* Wq = (const float*)d_in[1];
    const float* Wk = (const float*)d_in[2];
    const float* Wv = (const float*)d_in[3];
    float* o = (float*)d_out;            // output fp32 (verified round 4)

    const size_t qkvb = (size_t)Bn * Tn * Hn;          // 4,194,304 elems
    unsigned short* Qb = (unsigned short*)d_ws;        // (B*T, H) bf16
    unsigned short* Kb = Qb + qkvb;
    unsigned short* Vb = Kb + qkvb;
    unsigned short* xbf = Vb + qkvb;                   // (B*T, E) bf16, 67 MB
    unsigned short* wt3 = xbf + (size_t)Bn * Tn * En;  // 3 x (H, E) bf16

    // split-K partials overlay the xbf region (dead after qkv2):
    // U = 2*Bn*Tn*Hn f32 (33.5 MB) + ML = 2*Bn*Tn float2 (0.5 MB) < 67 MB.
    float* Up = (float*)xbf;
    float2* MLp = (float2*)((char*)xbf + (size_t)2 * Bn * Tn * Hn * sizeof(float));

    const size_t ws_need = (3 * qkvb + (size_t)Bn * Tn * En + 3 * (size_t)Hn * En)
                           * sizeof(unsigned short);

    static bool attr_done = false;
    if (!attr_done) {
        hipFuncSetAttribute((const void*)flash_mfma,
                            hipFuncAttributeMaxDynamicSharedMemorySize, 81920);
        attr_done = true;
    }

    if (ws_size >= ws_need) {
        cvtall<<<8216, 256, 0, stream>>>(x, xbf, Wq, Wk, Wv, wt3);
        qkv2<<<dim3(256, 3), 512, 0, stream>>>(xbf, wt3, Qb, Kb, Vb);
        flash_mfma<<<dim3(8, 64, 2), 512, 81920, stream>>>(Qb, Kb, Vb, o, Up, MLp);
        fcomb<<<4096, 256, 0, stream>>>(Up, MLp, o);
    } else {
        qkv_mfma<<<dim3(256, 3), 256, 0, stream>>>(x, Wq, Wk, Wv, Qb, Kb, Vb);
        flash_mfma<<<dim3(8, 64, 1), 512, 81920, stream>>>(Qb, Kb, Vb, o,
                                                           nullptr, nullptr);
    }
}